// Round 11
// baseline (354.784 us; speedup 1.0000x reference)
//
#include <hip/hip_runtime.h>
#include <hip/hip_bf16.h>
#include <cstdint>

using bf16 = __hip_bfloat16;
typedef __attribute__((ext_vector_type(8))) short short8;
typedef __attribute__((ext_vector_type(4))) float f32x4;
typedef __attribute__((ext_vector_type(4))) unsigned u32x4;
typedef __attribute__((ext_vector_type(2))) unsigned u32x2;
typedef __attribute__((ext_vector_type(8))) int i32x8;
typedef __attribute__((ext_vector_type(4))) int i32x4;
typedef __attribute__((ext_vector_type(2))) int i32x2;

#define DI __device__ __forceinline__

constexpr int MROWS = 16384;   // B * S
constexpr int EMB   = 1024;
constexpr int HID   = 4096;

DI void gload16(const void* g, void* l) {
  __builtin_amdgcn_global_load_lds((const __attribute__((address_space(1))) void*)g,
                                   (__attribute__((address_space(3))) void*)l, 16, 0, 0);
}

#define SBAR()    __builtin_amdgcn_s_barrier()
#define WAITVM(n) asm volatile("s_waitcnt vmcnt(" #n ")" ::: "memory")

#define DPPMAX(x, ctrl) \
  x = fmaxf(x, __int_as_float(__builtin_amdgcn_update_dpp( \
          0, __float_as_int(x), ctrl, 0xf, 0xf, false)));
DI float redmax16(float x) {
  DPPMAX(x, 0xB1) DPPMAX(x, 0x4E) DPPMAX(x, 0x124) DPPMAX(x, 0x128)
  return x;
}

// e4m3 byte encoding n/8 for n = integer-valued float, |n| <= 16. Exact.
DI uint8_t enc8(float n) {
  unsigned b = __float_as_uint(n);
  unsigned s = (b >> 24) & 0x80u;
  unsigned e = (b >> 23) & 0xffu;
  return (uint8_t)(e ? (s | ((e - 123u) << 3) | ((b >> 20) & 7u)) : s);
}

// ============ convention probe ============
// A payload: 1.0 only in VGPR pair 0; B payload: all 1.0. All scales 1.0
// except scale-slot0 = 2.0 (replicated) on the single lane (l16==5, lhi==0).
// D[0][0] = 32 always.
//  slot0->A, contiguous(a): D[5][0]=40   slot0->A, stacked(b): D[5][0]=64
//  slot0->B, contiguous(a): D[0][5]=40   slot0->B, stacked(b): D[0][5]=64
// flag: 0=(A,a) 1=(A,b) 2=(B,a) 3=(B,b) 4=unknown
__global__ void mxprobe(int* flag) {
  i32x8 a, b;
#pragma unroll
  for (int i = 0; i < 8; i++) { a[i] = (i < 2) ? 0x38383838 : 0; b[i] = 0x38383838; }
  f32x4 c = {0.f, 0.f, 0.f, 0.f};
  const int l16 = threadIdx.x & 15, lhi = (threadIdx.x & 63) >> 4;
  int s0 = (l16 == 5 && lhi == 0) ? (int)0x80808080 : 0x7f7f7f7f;
  int s1 = 0x7f7f7f7f;
  f32x4 d = __builtin_amdgcn_mfma_scale_f32_16x16x128_f8f6f4(a, b, c, 0, 0, 0, s0, 0, s1);
  float x00 = __shfl(d[0], 0, 64);    // D[0][0]
  float x50 = __shfl(d[1], 16, 64);   // D[5][0]: row5 = lane>>4=1, reg1; col0
  float x05 = __shfl(d[0], 5, 64);    // D[0][5]
  if (threadIdx.x == 0) {
    int f = 4;
    if (x00 == 32.f) {
      if      (x50 == 40.f && x05 == 32.f) f = 0;
      else if (x50 == 64.f && x05 == 32.f) f = 1;
      else if (x05 == 40.f && x50 == 32.f) f = 2;
      else if (x05 == 64.f && x50 == 32.f) f = 3;
    }
    flag[0] = f;
  }
}

// ============ quant kernels ============
// fp8 path (runs when flag <= 3)
template<int BPRL, bool APACK>
__global__ void quant8(const float* __restrict__ in, uint8_t* __restrict__ out,
                       uint8_t* __restrict__ sT, int nblk, int nr,
                       const int* __restrict__ mxfl) {
  if (mxfl[0] > 3) return;
  int b = blockIdx.x * blockDim.x + threadIdx.x;
  if (b >= nblk) return;
  const f32x4* p = (const f32x4*)(in + (size_t)b * 32);
  f32x4 v[8]; float amax = 0.f;
#pragma unroll
  for (int i = 0; i < 8; i++) {
    v[i] = p[i];
    amax = fmaxf(amax, fmaxf(fmaxf(fabsf(v[i][0]), fabsf(v[i][1])),
                             fmaxf(fabsf(v[i][2]), fabsf(v[i][3]))));
  }
  int eb = (int)((__float_as_uint(amax) >> 23) & 255u); eb = eb < 4 ? 4 : eb;
  float inv = __uint_as_float((unsigned)(257 - eb) << 23);   // 2^(3-e)
  u32x4 d0, d1;
#pragma unroll
  for (int i = 0; i < 8; i++) {
    unsigned w = 0;
#pragma unroll
    for (int j = 0; j < 4; j++) w |= (unsigned)enc8(rintf(v[i][j] * inv)) << (j * 8);
    if (i < 4) d0[i] = w; else d1[i - 4] = w;
  }
  *(u32x4*)(out + (size_t)b * 32) = d0;
  *(u32x4*)(out + (size_t)b * 32 + 16) = d1;
  int row = b >> BPRL, blk = b & ((1 << BPRL) - 1);
  size_t si = APACK ? (size_t)((blk << 5) + (row & 31)) * (nr >> 5) + (row >> 5)
                    : (size_t)((blk << 4) + (row & 15)) * (nr >> 4) + (row >> 4);
  sT[si] = (uint8_t)eb;
}

// bf16 fallback quant (runs when flag == 4)
__global__ void quant32(const float* __restrict__ in, bf16* __restrict__ out, int nblk,
                        const int* __restrict__ mxfl) {
  if (mxfl[0] <= 3) return;
  int b = blockIdx.x * blockDim.x + threadIdx.x;
  if (b >= nblk) return;
  const f32x4* p = (const f32x4*)(in + (size_t)b * 32);
  f32x4 v[8]; float amax = 0.f;
#pragma unroll
  for (int i = 0; i < 8; i++) {
    v[i] = p[i];
    amax = fmaxf(amax, fmaxf(fmaxf(fabsf(v[i][0]), fabsf(v[i][1])),
                             fmaxf(fabsf(v[i][2]), fabsf(v[i][3]))));
  }
  int eb = (int)((__float_as_uint(amax) >> 23) & 255u); eb = eb < 4 ? 4 : eb;
  float scale = __uint_as_float((unsigned)(eb - 3) << 23);
  float inv   = __uint_as_float((unsigned)(257 - eb) << 23);
  alignas(16) unsigned short us[32];
#pragma unroll
  for (int i = 0; i < 8; i++)
#pragma unroll
    for (int j = 0; j < 4; j++)
      us[i * 4 + j] = (unsigned short)(__float_as_uint(rintf(v[i][j] * inv) * scale) >> 16);
  short8* o = (short8*)(out + (size_t)b * 32);
#pragma unroll
  for (int i = 0; i < 4; i++) o[i] = *(short8*)(us + i * 8);
}

// ============ MX fp8 GEMM ============
#define QUAD(MH, NH, BG, SAD, SBW) { \
  _Pragma("unroll") for (int mp = 0; mp < 2; mp++) { \
    i32x8 a0 = ldA(db, MH, mp * 2); \
    i32x8 a1 = ldA(db, MH, mp * 2 + 1); \
    __builtin_amdgcn_s_setprio(1); \
    _Pragma("unroll") for (int ni = 0; ni < 2; ni++) { \
      int sb = (int)(((unsigned)((SBW) >> (ni * 8)) & 0xffu) * 0x01010101u); \
      int s0 = (int)(((unsigned)((SAD) >> (mp * 16)) & 0xffu) * 0x01010101u); \
      int s1 = (int)(((unsigned)((SAD) >> (mp * 16 + 8)) & 0xffu) * 0x01010101u); \
      int p0 = fl ? sb : s0, q0 = fl ? s0 : sb; \
      int p1 = fl ? sb : s1, q1 = fl ? s1 : sb; \
      acc[(MH)*4+mp*2][(NH)*2+ni] = __builtin_amdgcn_mfma_scale_f32_16x16x128_f8f6f4( \
          a0, BG[ni], acc[(MH)*4+mp*2][(NH)*2+ni], 0, 0, 0, p0, 0, q0); \
      acc[(MH)*4+mp*2+1][(NH)*2+ni] = __builtin_amdgcn_mfma_scale_f32_16x16x128_f8f6f4( \
          a1, BG[ni], acc[(MH)*4+mp*2+1][(NH)*2+ni], 0, 0, 0, p1, 0, q1); \
    } \
    __builtin_amdgcn_s_setprio(0); \
  } }

// LAY=0: per-lane contiguous 32 bytes (k = lhi*32..+31).
// LAY=1: 4-stacked 16x16x32 (VGPR pair s: k = s*32 + lhi*8..+7).
template<int Kd, int Nd, bool GQ, int LAY>
__global__ void __launch_bounds__(512, 2)
mxgemm(const uint8_t* __restrict__ Ap, const uint8_t* __restrict__ Bp,
       const uint8_t* __restrict__ sA, const uint8_t* __restrict__ sB,
       const float* __restrict__ bias, void* __restrict__ Cout,
       uint8_t* __restrict__ sOut, const int* __restrict__ mxfl) {
  const int f = mxfl[0];
  if (f > 3 || (f & 1) != LAY) return;
  const int fl = (f >> 1) & 1;

  __shared__ alignas(16) uint8_t SH[131072];
  uint8_t* Abuf = SH;
  uint8_t* Bbuf = SH + 65536;

  const int tid = threadIdx.x;
  const int lane = tid & 63, wave = tid >> 6;
  const int l16 = lane & 15, lhi = lane >> 4;
  const int wr = wave >> 2, wc = wave & 3;

  const int idx = blockIdx.x >> 3, xid = blockIdx.x & 7;
  const int brow = (xid * 8 + (idx & 7)) * 256;
  const int bcol = (idx >> 3) * 256;

  const int r0 = tid >> 3;
  const int sl = (tid & 7) ^ (r0 & 7);
  const uint8_t* asrc = Ap + (size_t)(brow + r0) * Kd + sl * 16;
  const uint8_t* bsrc = Bp + (size_t)(bcol + r0) * Kd + sl * 16;

  auto stA = [&](int tt, int half) {
    const uint8_t* s = asrc + (size_t)half * 128 * Kd + tt * 128;
    uint8_t* d = Abuf + ((tt & 1) * 2 + half) * 16384 + tid * 16;
    gload16(s, d); gload16(s + (size_t)64 * Kd, d + 8192);
  };
  auto stB = [&](int tt, int half) {
    const uint8_t* s = bsrc + (size_t)half * 128 * Kd + tt * 128;
    uint8_t* d = Bbuf + ((tt & 1) * 2 + half) * 16384 + tid * 16;
    gload16(s, d); gload16(s + (size_t)64 * Kd, d + 8192);
  };

  const int sx = l16 & 7;
  auto ld8 = [&](const uint8_t* base) -> i32x8 {
    i32x8 r;
    if constexpr (LAY == 0) {
      i32x4 lo = *(const i32x4*)(base + (((lhi * 2 + 0) ^ sx) << 4));
      i32x4 hi = *(const i32x4*)(base + (((lhi * 2 + 1) ^ sx) << 4));
      r[0] = lo[0]; r[1] = lo[1]; r[2] = lo[2]; r[3] = lo[3];
      r[4] = hi[0]; r[5] = hi[1]; r[6] = hi[2]; r[7] = hi[3];
    } else {
#pragma unroll
      for (int s = 0; s < 4; s++) {
        i32x2 q = *(const i32x2*)(base + ((((s * 2 + (lhi >> 1)) ^ sx) << 4) + (lhi & 1) * 8));
        r[2 * s] = q[0]; r[2 * s + 1] = q[1];
      }
    }
    return r;
  };
  auto ldA = [&](int db, int mh, int mt) -> i32x8 {
    return ld8(Abuf + (db * 2 + mh) * 16384 + (mt * 32 + wr * 16 + l16) * 128);
  };
  auto ldB = [&](int db, int nh, int ni) -> i32x8 {
    return ld8(Bbuf + (db * 2 + nh) * 16384 + (wc * 32 + ni * 16 + l16) * 128);
  };

  u32x2 curA, nxA; unsigned curB0, curB1, nxB0, nxB1;
  auto gA = [&](int t) -> u32x2 {
    return *(const u32x2*)(sA + ((size_t)(4 * t + lhi) * 32 + wr * 16 + l16) * (MROWS >> 5)
                              + (brow >> 5));
  };
  auto gB = [&](int t, unsigned& b0, unsigned& b1) {
    const uint8_t* p = sB + ((size_t)(4 * t + lhi) * 16 + l16) * (Nd >> 4) + (bcol >> 4) + wc * 2;
    b0 = *(const unsigned short*)p;
    b1 = *(const unsigned short*)(p + 8);
  };

  f32x4 acc[8][4] = {};
  i32x8 bgl[2], bgh[2];

  constexpr int NT = Kd / 128;

  stA(0, 0); stB(0, 0); stB(0, 1); stA(0, 1);
  curA = gA(0); gB(0, curB0, curB1);
  stA(1, 0); stB(1, 0); stB(1, 1);
  WAITVM(6); SBAR();

  for (int t = 0; t <= NT - 3; ++t) {
    const int db = t & 1;
    bgl[0] = ldB(db, 0, 0); bgl[1] = ldB(db, 0, 1);
    bgh[0] = ldB(db, 1, 0); bgh[1] = ldB(db, 1, 1);
    nxA = gA(t + 1); gB(t + 1, nxB0, nxB1);
    stA(t + 1, 1);
    QUAD(0, 0, bgl, curA[0], curB0)
    QUAD(0, 1, bgh, curA[0], curB1)
    stA(t + 2, 0);
    QUAD(1, 0, bgl, curA[1], curB0)
    stB(t + 2, 0); stB(t + 2, 1);
    QUAD(1, 1, bgh, curA[1], curB1)
    WAITVM(6); SBAR();
    curA = nxA; curB0 = nxB0; curB1 = nxB1;
  }

  {
    const int db = (NT - 2) & 1;
    bgl[0] = ldB(db, 0, 0); bgl[1] = ldB(db, 0, 1);
    bgh[0] = ldB(db, 1, 0); bgh[1] = ldB(db, 1, 1);
    nxA = gA(NT - 1); gB(NT - 1, nxB0, nxB1);
    stA(NT - 1, 1);
    QUAD(0, 0, bgl, curA[0], curB0)
    QUAD(0, 1, bgh, curA[0], curB1)
    QUAD(1, 0, bgl, curA[1], curB0)
    QUAD(1, 1, bgh, curA[1], curB1)
    WAITVM(0); SBAR();
    curA = nxA; curB0 = nxB0; curB1 = nxB1;
  }

  {
    const int db = (NT - 1) & 1;
    bgl[0] = ldB(db, 0, 0); bgl[1] = ldB(db, 0, 1);
    bgh[0] = ldB(db, 1, 0); bgh[1] = ldB(db, 1, 1);
    QUAD(0, 0, bgl, curA[0], curB0)
    QUAD(0, 1, bgh, curA[0], curB1)
    QUAD(1, 0, bgl, curA[1], curB0)
    QUAD(1, 1, bgh, curA[1], curB1)
  }

  const int cb = bcol + wc * 32;
  float bv[4];
#pragma unroll
  for (int n = 0; n < 4; n++) bv[n] = bias[cb + (n >> 1) * 128 + (n & 1) * 16 + l16];

  if constexpr (GQ) {
    uint8_t* hq = (uint8_t*)Cout;
#pragma unroll
    for (int m = 0; m < 8; m++) {
#pragma unroll
      for (int r = 0; r < 4; r++) {
        float g[4];
#pragma unroll
        for (int n = 0; n < 4; n++) {
          float v = acc[m][n][r] + bv[n];
          g[n] = 0.5f * v * (1.0f + erff(v * 0.70710678118654752f));
        }
        const int row = brow + m * 32 + wr * 16 + lhi * 4 + r;
        const size_t ro = (size_t)row * Nd;
#pragma unroll
        for (int p = 0; p < 2; p++) {
          float am = redmax16(fmaxf(fabsf(g[p * 2]), fabsf(g[p * 2 + 1])));
          int eb = (int)((__float_as_uint(am) >> 23) & 255u); eb = eb < 4 ? 4 : eb;
          float iv = __uint_as_float((unsigned)(257 - eb) << 23);
          hq[ro + cb + p * 128 + l16]      = enc8(rintf(g[p * 2] * iv));
          hq[ro + cb + p * 128 + 16 + l16] = enc8(rintf(g[p * 2 + 1] * iv));
          if (l16 == 0) {
            const int blk = (cb >> 5) + p * 4;
            sOut[((size_t)((blk << 5) + (row & 31)) << 9) + (row >> 5)] = (uint8_t)eb;
          }
        }
      }
    }
  } else {
    float* outp = (float*)Cout;
#pragma unroll
    for (int m = 0; m < 8; m++) {
      const size_t rbase = (size_t)(brow + m * 32 + wr * 16 + lhi * 4);
#pragma unroll
      for (int r = 0; r < 4; r++) {
        const size_t ro = (rbase + r) * Nd;
#pragma unroll
        for (int n = 0; n < 4; n++)
          __builtin_nontemporal_store(acc[m][n][r] + bv[n],
              &outp[ro + cb + (n >> 1) * 128 + (n & 1) * 16 + l16]);
      }
    }
  }
}

// ============ bf16 fallback GEMM (proven R7) ============
#define BMFMA(a, b, c) __builtin_amdgcn_mfma_f32_16x16x32_bf16(a, b, c, 0, 0, 0)
#define BQ_MFMA(MB, NB, BG) \
  __builtin_amdgcn_s_setprio(1); \
  _Pragma("unroll") for (int kk = 0; kk < 2; kk++) \
  _Pragma("unroll") for (int mi = 0; mi < 4; mi++) \
  _Pragma("unroll") for (int ni = 0; ni < 2; ni++) \
    acc[(MB) + mi][(NB) + ni] = BMFMA(af[mi * 2 + kk], BG[ni * 2 + kk], acc[(MB) + mi][(NB) + ni]); \
  __builtin_amdgcn_s_setprio(0);
#define BRD_AF(mh) \
  _Pragma("unroll") for (int mi = 0; mi < 4; mi++) { \
    af[mi * 2]     = ldA(db, mh, mi, 0); \
    af[mi * 2 + 1] = ldA(db, mh, mi, 1); }
#define BRD_B(half, dst) \
  _Pragma("unroll") for (int ni = 0; ni < 2; ni++) { \
    dst[ni * 2]     = ldB(db, half, ni, 0); \
    dst[ni * 2 + 1] = ldB(db, half, ni, 1); }

template<int Kd, int Nd, bool GQ>
__global__ void __launch_bounds__(512, 2)
bgemm(const bf16* __restrict__ Ap, const bf16* __restrict__ Bp,
      const float* __restrict__ bias, void* __restrict__ Cout,
      const int* __restrict__ mxfl) {
  if (mxfl[0] <= 3) return;
  __shared__ alignas(16) bf16 SH[65536];
  bf16* Abuf = SH;
  bf16* Bbuf = SH + 32768;

  const int tid  = threadIdx.x;
  const int lane = tid & 63, wave = tid >> 6;
  const int l16  = lane & 15, lhi = lane >> 4;
  const int wr   = wave >> 2, wc  = wave & 3;

  const int idx  = blockIdx.x >> 3;
  const int xid  = blockIdx.x & 7;
  const int brow = (xid * 8 + (idx & 7)) * 256;
  const int bcol = (idx >> 3) * 256;

  const int r0 = tid >> 3;
  const int sl = (tid & 7) ^ (r0 & 7);
  const bf16* asrc = Ap + (size_t)(brow + r0) * Kd + sl * 8;
  const bf16* bsrc = Bp + (size_t)(bcol + r0) * Kd + sl * 8;

  auto stA = [&](int tt, int half) {
    const bf16* s = asrc + (size_t)half * 128 * Kd + tt * 64;
    bf16* d = Abuf + ((tt & 1) * 2 + half) * 8192 + tid * 8;
    gload16(s, d); gload16(s + (size_t)64 * Kd, d + 4096);
  };
  auto stB = [&](int tt, int half) {
    const bf16* s = bsrc + (size_t)half * 128 * Kd + tt * 64;
    bf16* d = Bbuf + ((tt & 1) * 2 + half) * 8192 + tid * 8;
    gload16(s, d); gload16(s + (size_t)64 * Kd, d + 4096);
  };

  const int sx = l16 & 7;
  const int arow = wr * 16 + l16;
  auto ldA = [&](int db, int mh, int mi, int kk) -> short8 {
    return *(const short8*)(Abuf + (db * 2 + mh) * 8192 +
                            (mi * 32 + arow) * 64 + ((kk * 4 + lhi) ^ sx) * 8);
  };
  const int brl = wc * 32 + l16;
  auto ldB = [&](int db, int half, int ni, int kk) -> short8 {
    return *(const short8*)(Bbuf + (db * 2 + half) * 8192 +
                            (brl + ni * 16) * 64 + ((kk * 4 + lhi) ^ sx) * 8);
  };

  f32x4 acc[8][4] = {};
  short8 af[8], bgl[4], bgh[4];
  constexpr int NT = Kd / 64;

  stA(0, 0); stB(0, 0); stB(0, 1); stA(0, 1);
  stA(1, 0); stB(1, 0); stB(1, 1);
  WAITVM(6); SBAR();

  for (int t = 0; t <= NT - 3; ++t) {
    const int db = t & 1;
    BRD_AF(0) BRD_B(0, bgl) BRD_B(1, bgh)
    stA(t + 1, 1);
    BQ_MFMA(0, 0, bgl)
    stA(t + 2, 0);
    BQ_MFMA(0, 2, bgh)
    stB(t + 2, 0);
    BRD_AF(1)
    stB(t + 2, 1);
    BQ_MFMA(4, 0, bgl)
    BQ_MFMA(4, 2, bgh)
    WAITVM(6); SBAR();
  }
  {
    const int db = (NT - 2) & 1;
    BRD_AF(0) BRD_B(0, bgl) BRD_B(1, bgh)
    stA(NT - 1, 1);
    BQ_MFMA(0, 0, bgl)
    BQ_MFMA(0, 2, bgh)
    BRD_AF(1)
    BQ_MFMA(4, 0, bgl)
    BQ_MFMA(4, 2, bgh)
    WAITVM(0); SBAR();
  }
  {
    const int db = (NT - 1) & 1;
    BRD_AF(0) BRD_B(0, bgl) BRD_B(1, bgh)
    BQ_MFMA(0, 0, bgl)
    BQ_MFMA(0, 2, bgh)
    BRD_AF(1)
    BQ_MFMA(4, 0, bgl)
    BQ_MFMA(4, 2, bgh)
  }

  const int cb = bcol + wc * 32;
  float bv[4];
#pragma unroll
  for (int n = 0; n < 4; n++) bv[n] = bias[cb + (n >> 1) * 128 + (n & 1) * 16 + l16];

  if constexpr (GQ) {
    bf16* outp = (bf16*)Cout;
#pragma unroll
    for (int mh2 = 0; mh2 < 2; mh2++) {
      __syncthreads();
#pragma unroll
      for (int mm = 0; mm < 4; mm++) {
        const int m = mh2 * 4 + mm;
        const int rl0 = mm * 32 + wr * 16 + lhi * 4;
#pragma unroll
        for (int r = 0; r < 4; r++) {
          float g[4];
#pragma unroll
          for (int n = 0; n < 4; n++) {
            float v = acc[m][n][r] + bv[n];
            g[n] = 0.5f * v * (1.0f + erff(v * 0.70710678118654752f));
          }
          const int rowb = (rl0 + r) * 256;
#pragma unroll
          for (int p = 0; p < 2; p++) {
            float am = redmax16(fmaxf(fabsf(g[p * 2]), fabsf(g[p * 2 + 1])));
            int eb = (int)((__float_as_uint(am) >> 23) & 255u); eb = eb < 4 ? 4 : eb;
            float sc = __uint_as_float((unsigned)(eb - 3) << 23);
            float iv = __uint_as_float((unsigned)(257 - eb) << 23);
            const int c0 = wc * 32 + p * 128;
            SH[rowb + ((c0 + l16)      ^ (lhi << 4))] = __float2bfloat16(rintf(g[p * 2]     * iv) * sc);
            SH[rowb + ((c0 + 16 + l16) ^ (lhi << 4))] = __float2bfloat16(rintf(g[p * 2 + 1] * iv) * sc);
          }
        }
      }
      __syncthreads();
#pragma unroll
      for (int i = 0; i < 8; i++) {
        const int c   = i * 512 + tid;
        const int row = c >> 5, cc = c & 31;
        const int scc = cc ^ (((row >> 2) & 3) << 1);
        *(short8*)((bf16*)Cout + (size_t)(brow + mh2 * 128 + row) * Nd + bcol + cc * 8) =
            *(const short8*)(SH + (size_t)row * 256 + scc * 8);
      }
    }
    (void)outp;
  } else {
    float* outp = (float*)Cout;
#pragma unroll
    for (int m = 0; m < 8; m++) {
      const size_t rbase = (size_t)(brow + m * 32 + wr * 16 + lhi * 4);
#pragma unroll
      for (int r = 0; r < 4; r++) {
        const size_t ro = (rbase + r) * Nd;
#pragma unroll
        for (int n = 0; n < 4; n++)
          __builtin_nontemporal_store(acc[m][n][r] + bv[n],
              &outp[ro + cb + (n >> 1) * 128 + (n & 1) * 16 + l16]);
      }
    }
  }
}

extern "C" void kernel_launch(void* const* d_in, const int* in_sizes, int n_in,
                              void* d_out, int out_size, void* d_ws, size_t ws_size,
                              hipStream_t stream) {
  const float* x      = (const float*)d_in[0];
  const float* w_fc   = (const float*)d_in[1];
  const float* b_fc   = (const float*)d_in[2];
  const float* w_proj = (const float*)d_in[3];
  const float* b_proj = (const float*)d_in[4];

  char* base = (char*)d_ws;
  const size_t MB = 1ull << 20;
  int* mxfl = (int*)(base + ws_size - 4096);

  // MX regions (used when flag <= 3)
  uint8_t* xq8  = (uint8_t*)(base);
  uint8_t* wfq8 = (uint8_t*)(base + 16 * MB);
  uint8_t* wpq8 = (uint8_t*)(base + 20 * MB);
  uint8_t* hq8  = (uint8_t*)(base + 24 * MB);
  uint8_t* sxA  = (uint8_t*)(base + 88 * MB);
  uint8_t* swfc = (uint8_t*)(base + 88 * MB + 512 * 1024);
  uint8_t* swpj = (uint8_t*)(base + 88 * MB + 640 * 1024);
  uint8_t* shA  = (uint8_t*)(base + 89 * MB);
  // bf16 fallback regions (used when flag == 4); alias MX regions (time-gated)
  bf16* xqb  = (bf16*)(base);
  bf16* wfqb = (bf16*)(base + 32 * MB);
  bf16* wpqb = (bf16*)(base + 40 * MB);
  bf16* hqb  = (bf16*)(base + 48 * MB);
  const bool dual = ws_size >= 177 * MB;

  mxprobe<<<1, 64, 0, stream>>>(mxfl);

  quant8<5, true ><<<2048, 256, 0, stream>>>(x,      xq8,  sxA,  MROWS * EMB / 32, MROWS, mxfl);
  quant8<5, false><<< 512, 256, 0, stream>>>(w_fc,   wfq8, swfc, HID * EMB / 32,   HID,   mxfl);
  quant8<7, false><<< 512, 256, 0, stream>>>(w_proj, wpq8, swpj, EMB * HID / 32,   EMB,   mxfl);
  if (dual) {
    quant32<<<2048, 256, 0, stream>>>(x,      xqb,  MROWS * EMB / 32, mxfl);
    quant32<<< 512, 256, 0, stream>>>(w_fc,   wfqb, HID * EMB / 32,   mxfl);
    quant32<<< 512, 256, 0, stream>>>(w_proj, wpqb, EMB * HID / 32,   mxfl);
  }

  const int g1 = (MROWS / 256) * (HID / 256);
  const int g2 = (MROWS / 256) * (EMB / 256);
  mxgemm<EMB, HID, true, 0><<<g1, 512, 0, stream>>>(xq8, wfq8, sxA, swfc, b_fc, hq8, shA, mxfl);
  mxgemm<EMB, HID, true, 1><<<g1, 512, 0, stream>>>(xq8, wfq8, sxA, swfc, b_fc, hq8, shA, mxfl);
  if (dual)
    bgemm<EMB, HID, true ><<<g1, 512, 0, stream>>>(xqb, wfqb, b_fc, hqb, mxfl);

  mxgemm<HID, EMB, false, 0><<<g2, 512, 0, stream>>>(hq8, wpq8, shA, swpj, b_proj, (float*)d_out, nullptr, mxfl);
  mxgemm<HID, EMB, false, 1><<<g2, 512, 0, stream>>>(hq8, wpq8, shA, swpj, b_proj, (float*)d_out, nullptr, mxfl);
  if (dual)
    bgemm<HID, EMB, false><<<g2, 512, 0, stream>>>(hqb, wpqb, b_proj, (float*)d_out, mxfl);
}